// Round 9
// baseline (129.548 us; speedup 1.0000x reference)
//
#include <hip/hip_runtime.h>
#include <math.h>

#define N_NODES 2048
#define N_EDGES 4096
#define PI_F 3.14159265358979323846f
#define TWO_PI_F 6.28318530717958647692f

#define SBLK 256                 // scan grid: 1 block/CU
#define STHR 256
#define NSCAN (SBLK * STHR)      // 65536 scan threads
#define TOT4 (N_NODES * N_EDGES / 4)   // 2,097,152 float4s per matrix

// ---- device-coherent (cross-XCD) scalar access for MUTABLE data only.
__device__ __forceinline__ float agent_load(const float* p) {
    return __hip_atomic_load(p, __ATOMIC_RELAXED, __HIP_MEMORY_SCOPE_AGENT);
}
__device__ __forceinline__ int agent_load_i(const int* p) {
    return __hip_atomic_load(p, __ATOMIC_RELAXED, __HIP_MEMORY_SCOPE_AGENT);
}

// ================= 16-amplitude 4-wire sub-circuit =================
// Bit map: wire W0->bit8, W1->bit4, W2->bit2, W3->bit1.
// Gate template (both circuit families factorize to this; verified
// gate-by-gate vs EDGE_OPS/NODE_OPS; r4-r8 bench absmax=0):
//   RY(t0,W0) RY(t1,W1) CX(W0,W1) RY(t2,W2) RY(t3,W3) CX(W3,W2)
//   RY(t4,W1) RY(t5,W2)
//   A-type: CX(W1,W2) RY(t6,W2)   -> returns <Z_W2>
//   B-type: CX(W2,W1) RY(t6,W1)   -> returns <Z_W1>, <X_W1>

template<int M>
__device__ __forceinline__ void ry16(float* a, float c, float s) {
#pragma unroll
    for (int i = 0; i < 16; ++i)
        if (!(i & M)) {
            int j = i | M;
            float x0 = a[i], x1 = a[j];
            a[i] = c * x0 - s * x1;
            a[j] = s * x0 + c * x1;
        }
}
template<int MC, int MT>
__device__ __forceinline__ void cx16(float* a) {
#pragma unroll
    for (int i = 0; i < 16; ++i)
        if ((i & MC) && !(i & MT)) {
            int j = i | MT;
            float t = a[i]; a[i] = a[j]; a[j] = t;
        }
}

template<bool BTYPE>
__device__ __forceinline__ void sub16(const float* ic, const float* is,
                                      const float* thc, const float* ths,
                                      float& z, float& x) {
    float a[16];
    a[0] = ic[3]; a[1] = is[3];
#pragma unroll
    for (int i = 0; i < 2; ++i) { a[i | 2] = a[i] * is[2]; a[i] *= ic[2]; }
#pragma unroll
    for (int i = 0; i < 4; ++i) { a[i | 4] = a[i] * is[1]; a[i] *= ic[1]; }
#pragma unroll
    for (int i = 0; i < 8; ++i) { a[i | 8] = a[i] * is[0]; a[i] *= ic[0]; }
    ry16<8>(a, thc[0], ths[0]);
    ry16<4>(a, thc[1], ths[1]);
    cx16<8, 4>(a);
    ry16<2>(a, thc[2], ths[2]);
    ry16<1>(a, thc[3], ths[3]);
    cx16<1, 2>(a);
    ry16<4>(a, thc[4], ths[4]);
    ry16<2>(a, thc[5], ths[5]);
    if (BTYPE) { cx16<2, 4>(a); ry16<4>(a, thc[6], ths[6]); }
    else       { cx16<4, 2>(a); ry16<2>(a, thc[6], ths[6]); }
    const int m = BTYPE ? 4 : 2;
    z = 0.f; x = 0.f;
#pragma unroll
    for (int i = 0; i < 16; ++i) z += (i & m) ? -a[i] * a[i] : a[i] * a[i];
    if (BTYPE) {
#pragma unroll
        for (int i = 0; i < 16; ++i) if (!(i & 4)) x += a[i] * a[i | 4];
        x *= 2.f;
    }
}

// ---------------- scan: Ri/Ro one-hot -> send/recv/deg --------------------
// Pure-bandwidth: 64 MB read, plain stores (kernel boundary publishes).
__global__ __launch_bounds__(256) void k_scan(
        const float* __restrict__ Ri, const float* __restrict__ Ro,
        int* __restrict__ send, int* __restrict__ recv, int* __restrict__ deg) {
    int gid = blockIdx.x * STHR + threadIdx.x;
    const float4* Ri4 = (const float4*)Ri;
    const float4* Ro4 = (const float4*)Ro;
    // TOT4 = 4 * 8 * NSCAN exactly -> 4 iterations, no guards.
#pragma unroll 1
    for (int t0 = gid; t0 < TOT4; t0 += 8 * NSCAN) {
        float4 vi[8], vo[8];
#pragma unroll
        for (int u = 0; u < 8; ++u) {              // 16 loads in flight
            int t = t0 + u * NSCAN;
            vi[u] = Ri4[t]; vo[u] = Ro4[t];
        }
#pragma unroll
        for (int u = 0; u < 8; ++u) {
            int t = t0 + u * NSCAN;
            int base = t * 4;
            int row = base >> 12;                  // 4096 floats per row
            int e   = base & (N_EDGES - 1);
            int cnt = 0;
            if (vi[u].x != 0.f) { recv[e+0] = row; ++cnt; }
            if (vi[u].y != 0.f) { recv[e+1] = row; ++cnt; }
            if (vi[u].z != 0.f) { recv[e+2] = row; ++cnt; }
            if (vi[u].w != 0.f) { recv[e+3] = row; ++cnt; }
            if (vo[u].x != 0.f) { send[e+0] = row; ++cnt; }
            if (vo[u].y != 0.f) { send[e+1] = row; ++cnt; }
            if (vo[u].z != 0.f) { send[e+2] = row; ++cnt; }
            if (vo[u].w != 0.f) { send[e+3] = row; ++cnt; }
            if (cnt) atomicAdd(&deg[row], cnt);    // deg[n] = indeg + outdeg
        }
    }
}

// edge scatter: mi[ri] += ev*Hs, mo[si] += ev*Hr; drain own vmem queue
// (atomics performed at coherence point), then tick both arrival counters.
__device__ __forceinline__ void scatter8(float ev, float hs, float hr,
                                         float xs0, float xs1, float xs2,
                                         float xr0, float xr1, float xr2,
                                         int si, int ri,
                                         float* __restrict__ macc, int* __restrict__ arr) {
    atomicAdd(&macc[ri*8+0], ev*hs);  atomicAdd(&macc[ri*8+1], ev*xs0);
    atomicAdd(&macc[ri*8+2], ev*xs1); atomicAdd(&macc[ri*8+3], ev*xs2);
    atomicAdd(&macc[si*8+4], ev*hr);  atomicAdd(&macc[si*8+5], ev*xr0);
    atomicAdd(&macc[si*8+6], ev*xr1); atomicAdd(&macc[si*8+7], ev*xr2);
    asm volatile("s_waitcnt vmcnt(0)" ::: "memory");
    atomicAdd(&arr[ri], 1); atomicAdd(&arr[si], 1);
}

// ---------------- dataflow: 64 blocks x 64 threads, 1 edge/lane ------------
// Static data (send/recv/deg/X/W/b/te/tn) via PLAIN loads (kernel boundary
// published). Mutable exchange (macc/arr) via device atomics + agent loads.
// Per round: [wait-shadow zB9] poll arr -> gather macc -> redundant
// node_update of both endpoints (bitwise-identical across replicas) -> pubs
// -> ev -> scatter/out. Exactly 2 exchange rounds + final combine.
__global__ __launch_bounds__(64) void k_mega(
        const float* __restrict__ X, const float* __restrict__ W,
        const float* __restrict__ b, const float* __restrict__ te,
        const float* __restrict__ tn,
        const int* __restrict__ send, const int* __restrict__ recv,
        const int* __restrict__ deg,
        float* __restrict__ maccA, float* __restrict__ maccB,
        int* __restrict__ arrA, int* __restrict__ arrB,
        float* __restrict__ out) {
    __shared__ float s_teC[16], s_teS[16], s_tnC[24], s_tnS[24];
    int tid = threadIdx.x;

    // lane-uniform trig tables -> LDS
    if (tid < 14) {
        float s, c; __sincosf(0.5f * te[tid], &s, &c);
        s_teC[tid] = c; s_teS[tid] = s;
    } else if (tid == 14) {                        // full angle for ev combine
        float s, c; __sincosf(te[14], &s, &c);
        s_teC[14] = c; s_teS[14] = s;
    } else if (tid < 15 + 22) {
        int k = tid - 15; float s, c;
        if (k == 20) __sincosf(tn[20], &s, &c);    // full angle
        else         __sincosf(0.5f * tn[k], &s, &c);
        s_tnC[k] = c; s_tnS[k] = s;
    }
    __syncthreads();

    int e = blockIdx.x * 64 + tid;
    int si = send[e], ri = recv[e];                // plain (boundary-published)
    int dgs = deg[si], dgr = deg[ri];

    // local endpoint init (X/W/b immutable -> plain loads)
    float xs0 = X[si*3+0], xs1 = X[si*3+1], xs2 = X[si*3+2];
    float xr0 = X[ri*3+0], xr1 = X[ri*3+1], xr2 = X[ri*3+2];
    float w0 = W[0], w1 = W[1], w2 = W[2], bb = b[0];
    float hs = TWO_PI_F / (1.f + __expf(-(xs0*w0 + xs1*w1 + xs2*w2 + bb)));
    float hr = TWO_PI_F / (1.f + __expf(-(xr0*w0 + xr1*w1 + xr2*w2 + bb)));
    float chs, shs, chr, shr, cxs[3], sxs[3], cxr[3], sxr[3];
    __sincosf(0.5f*hs,  &shs,    &chs);
    __sincosf(0.5f*xs0, &sxs[0], &cxs[0]);
    __sincosf(0.5f*xs1, &sxs[1], &cxs[1]);
    __sincosf(0.5f*xs2, &sxs[2], &cxs[2]);
    __sincosf(0.5f*hr,  &shr,    &chr);
    __sincosf(0.5f*xr0, &sxr[0], &cxr[0]);
    __sincosf(0.5f*xr1, &sxr[1], &cxr[1]);
    __sincosf(0.5f*xr2, &sxr[2], &cxr[2]);
    float C14 = s_teC[14], S14 = s_teS[14];
    float C20 = s_tnC[20], S20 = s_tnS[20];

    float zA, zB, xB, dmy;
    {   // sender pub: A'-type, te{0,1,2,3,8,9,12}, <Z2>
        float ic[4] = {chs, cxs[0], cxs[1], cxs[2]};
        float is[4] = {shs, sxs[0], sxs[1], sxs[2]};
        float thc[7] = {s_teC[0],s_teC[1],s_teC[2],s_teC[3],s_teC[8],s_teC[9],s_teC[12]};
        float ths[7] = {s_teS[0],s_teS[1],s_teS[2],s_teS[3],s_teS[8],s_teS[9],s_teS[12]};
        sub16<false>(ic, is, thc, ths, zA, dmy);
    }
    {   // receiver pub: B'-type, te{4,5,6,7,10,11,13}, <Z5>,<X5>
        float ic[4] = {chr, cxr[0], cxr[1], cxr[2]};
        float is[4] = {shr, sxr[0], sxr[1], sxr[2]};
        float thc[7] = {s_teC[4],s_teC[5],s_teC[6],s_teC[7],s_teC[10],s_teC[11],s_teC[13]};
        float ths[7] = {s_teS[4],s_teS[5],s_teS[6],s_teS[7],s_teS[10],s_teS[11],s_teS[13]};
        sub16<true>(ic, is, thc, ths, zB, xB);
    }
    float ev = 0.5f*(1.f - (C14*zA*zB - S14*xB));
    scatter8(ev, hs, hr, xs0, xs1, xs2, xr0, xr1, xr2, si, ri, maccA, arrA);

#pragma unroll
    for (int it = 0; it < 2; ++it) {
        float* mc_ = it ? maccB : maccA;
        int*   ar  = it ? arrB  : arrA;
        // wait shadow: zB9 of both endpoints depends only on OWN old h
        float zB9s, zB9r;
        {
            float thc[7] = {s_tnC[8],s_tnC[9],s_tnC[10],s_tnC[11],s_tnC[16],s_tnC[17],s_tnC[21]};
            float ths[7] = {s_tnS[8],s_tnS[9],s_tnS[10],s_tnS[11],s_tnS[16],s_tnS[17],s_tnS[21]};
            float ic[4] = {chs, cxs[0], cxs[1], cxs[2]};
            float is[4] = {shs, sxs[0], sxs[1], sxs[2]};
            sub16<true>(ic, is, thc, ths, zB9s, dmy);
            float ic2[4] = {chr, cxr[0], cxr[1], cxr[2]};
            float is2[4] = {shr, sxr[0], sxr[1], sxr[2]};
            sub16<true>(ic2, is2, thc, ths, zB9r, dmy);
        }
        // single coherence hop: all edges of both endpoints have scattered
        while (agent_load_i(ar + si) < dgs || agent_load_i(ar + ri) < dgr) {}
        asm volatile("" ::: "memory");
        float Ms[8], Mr[8];
#pragma unroll
        for (int k = 0; k < 8; ++k) Ms[k] = agent_load(mc_ + si*8 + k);
#pragma unroll
        for (int k = 0; k < 8; ++k) Mr[k] = agent_load(mc_ + ri*8 + k);

        // redundant node updates (identical op sequence in every replica)
        float mCs[8], mSs[8], mCr[8], mSr[8];
#pragma unroll
        for (int k = 0; k < 8; ++k) __sincosf(0.5f*Ms[k], &mSs[k], &mCs[k]);
#pragma unroll
        for (int k = 0; k < 8; ++k) __sincosf(0.5f*Mr[k], &mSr[k], &mCr[k]);
        float thcA1[7] = {s_tnC[0],s_tnC[1],s_tnC[2],s_tnC[3],s_tnC[12],s_tnC[13],s_tnC[18]};
        float thsA1[7] = {s_tnS[0],s_tnS[1],s_tnS[2],s_tnS[3],s_tnS[12],s_tnS[13],s_tnS[18]};
        float thcA2[7] = {s_tnC[4],s_tnC[5],s_tnC[6],s_tnC[7],s_tnC[14],s_tnC[15],s_tnC[19]};
        float thsA2[7] = {s_tnS[4],s_tnS[5],s_tnS[6],s_tnS[7],s_tnS[14],s_tnS[15],s_tnS[19]};
        float zA1, zA2, xA2;
        sub16<false>(&mCs[0], &mSs[0], thcA1, thsA1, zA1, dmy);
        sub16<true >(&mCs[4], &mSs[4], thcA2, thsA2, zA2, xA2);
        hs = PI_F * (1.f - (C20*zA1*zA2 - S20*xA2) * zB9s);
        __sincosf(0.5f*hs, &shs, &chs);
        sub16<false>(&mCr[0], &mSr[0], thcA1, thsA1, zA1, dmy);
        sub16<true >(&mCr[4], &mSr[4], thcA2, thsA2, zA2, xA2);
        hr = PI_F * (1.f - (C20*zA1*zA2 - S20*xA2) * zB9r);
        __sincosf(0.5f*hr, &shr, &chr);

        {   // new sender pub
            float ic[4] = {chs, cxs[0], cxs[1], cxs[2]};
            float is[4] = {shs, sxs[0], sxs[1], sxs[2]};
            float thc[7] = {s_teC[0],s_teC[1],s_teC[2],s_teC[3],s_teC[8],s_teC[9],s_teC[12]};
            float ths[7] = {s_teS[0],s_teS[1],s_teS[2],s_teS[3],s_teS[8],s_teS[9],s_teS[12]};
            sub16<false>(ic, is, thc, ths, zA, dmy);
        }
        {   // new receiver pub
            float ic[4] = {chr, cxr[0], cxr[1], cxr[2]};
            float is[4] = {shr, sxr[0], sxr[1], sxr[2]};
            float thc[7] = {s_teC[4],s_teC[5],s_teC[6],s_teC[7],s_teC[10],s_teC[11],s_teC[13]};
            float ths[7] = {s_teS[4],s_teS[5],s_teS[6],s_teS[7],s_teS[10],s_teS[11],s_teS[13]};
            sub16<true>(ic, is, thc, ths, zB, xB);
        }
        ev = 0.5f*(1.f - (C14*zA*zB - S14*xB));
        if (it == 0) {
            scatter8(ev, hs, hr, xs0, xs1, xs2, xr0, xr1, xr2, si, ri, maccB, arrB);
        } else {
            out[e] = ev;
        }
    }
}

extern "C" void kernel_launch(void* const* d_in, const int* in_sizes, int n_in,
                              void* d_out, int out_size, void* d_ws, size_t ws_size,
                              hipStream_t stream) {
    const float* X  = (const float*)d_in[0];
    const float* Ri = (const float*)d_in[1];
    const float* Ro = (const float*)d_in[2];
    const float* W  = (const float*)d_in[3];
    const float* b  = (const float*)d_in[4];
    const float* te = (const float*)d_in[5];
    const float* tn = (const float*)d_in[6];
    float* out = (float*)d_out;

    int*   send  = (int*)d_ws;                      // [4096] (fully scan-written)
    int*   recv  = send + N_EDGES;                  // [4096]
    // ---- zero region: macc + arr + deg ----
    float* maccA = (float*)(recv + N_EDGES);        // [16384]
    float* maccB = maccA + N_NODES * 8;             // [16384]
    int*   arrA  = (int*)(maccB + N_NODES * 8);     // [2048]
    int*   arrB  = arrA + N_NODES;                  // [2048]
    int*   deg   = arrB + N_NODES;                  // [2048]
    size_t zbytes = (size_t)(2*N_NODES*8 + 3*N_NODES) * 4;

    hipMemsetAsync((void*)maccA, 0, zbytes, stream);
    k_scan<<<SBLK, STHR, 0, stream>>>(Ri, Ro, send, recv, deg);
    k_mega<<<64, 64, 0, stream>>>(X, W, b, te, tn, send, recv, deg,
                                  maccA, maccB, arrA, arrB, out);
}

// Round 10
// 126.782 us; speedup vs baseline: 1.0218x; 1.0218x over previous
//
#include <hip/hip_runtime.h>
#include <math.h>

#define N_NODES 2048
#define N_EDGES 4096
#define PI_F 3.14159265358979323846f
#define TWO_PI_F 6.28318530717958647692f

// ---- device-coherent (cross-XCD) scalar access: bypass non-coherent L1/L2.
__device__ __forceinline__ float agent_load(const float* p) {
    return __hip_atomic_load(p, __ATOMIC_RELAXED, __HIP_MEMORY_SCOPE_AGENT);
}
__device__ __forceinline__ int agent_load_i(const int* p) {
    return __hip_atomic_load(p, __ATOMIC_RELAXED, __HIP_MEMORY_SCOPE_AGENT);
}
__device__ __forceinline__ void agent_store(float* p, float v) {
    __hip_atomic_store(p, v, __ATOMIC_RELAXED, __HIP_MEMORY_SCOPE_AGENT);
}
__device__ __forceinline__ void agent_store_i(int* p, int v) {
    __hip_atomic_store(p, v, __ATOMIC_RELAXED, __HIP_MEMORY_SCOPE_AGENT);
}
__device__ __forceinline__ void spin_ge(const int* p, int v) {
    while (__hip_atomic_load(p, __ATOMIC_RELAXED, __HIP_MEMORY_SCOPE_AGENT) < v)
        __builtin_amdgcn_s_sleep(2);
    asm volatile("" ::: "memory");
}

// ================= 16-amplitude 4-wire sub-circuit =================
// Bit map: wire W0->bit8, W1->bit4, W2->bit2, W3->bit1.
// Gate template (both circuit families factorize to this; verified
// gate-by-gate vs EDGE_OPS/NODE_OPS; r4-r9 bench absmax=0):
//   RY(t0,W0) RY(t1,W1) CX(W0,W1) RY(t2,W2) RY(t3,W3) CX(W3,W2)
//   RY(t4,W1) RY(t5,W2)
//   A-type: CX(W1,W2) RY(t6,W2)   -> returns <Z_W2>
//   B-type: CX(W2,W1) RY(t6,W1)   -> returns <Z_W1>, <X_W1>

template<int M>
__device__ __forceinline__ void ry16(float* a, float c, float s) {
#pragma unroll
    for (int i = 0; i < 16; ++i)
        if (!(i & M)) {
            int j = i | M;
            float x0 = a[i], x1 = a[j];
            a[i] = c * x0 - s * x1;
            a[j] = s * x0 + c * x1;
        }
}
template<int MC, int MT>
__device__ __forceinline__ void cx16(float* a) {
#pragma unroll
    for (int i = 0; i < 16; ++i)
        if ((i & MC) && !(i & MT)) {
            int j = i | MT;
            float t = a[i]; a[i] = a[j]; a[j] = t;
        }
}

template<bool BTYPE>
__device__ __forceinline__ void sub16(const float* ic, const float* is,
                                      const float* thc, const float* ths,
                                      float& z, float& x) {
    float a[16];
    a[0] = ic[3]; a[1] = is[3];
#pragma unroll
    for (int i = 0; i < 2; ++i) { a[i | 2] = a[i] * is[2]; a[i] *= ic[2]; }
#pragma unroll
    for (int i = 0; i < 4; ++i) { a[i | 4] = a[i] * is[1]; a[i] *= ic[1]; }
#pragma unroll
    for (int i = 0; i < 8; ++i) { a[i | 8] = a[i] * is[0]; a[i] *= ic[0]; }
    ry16<8>(a, thc[0], ths[0]);
    ry16<4>(a, thc[1], ths[1]);
    cx16<8, 4>(a);
    ry16<2>(a, thc[2], ths[2]);
    ry16<1>(a, thc[3], ths[3]);
    cx16<1, 2>(a);
    ry16<4>(a, thc[4], ths[4]);
    ry16<2>(a, thc[5], ths[5]);
    if (BTYPE) { cx16<2, 4>(a); ry16<4>(a, thc[6], ths[6]); }
    else       { cx16<4, 2>(a); ry16<2>(a, thc[6], ths[6]); }
    const int m = BTYPE ? 4 : 2;
    z = 0.f; x = 0.f;
#pragma unroll
    for (int i = 0; i < 16; ++i) z += (i & m) ? -a[i] * a[i] : a[i] * a[i];
    if (BTYPE) {
#pragma unroll
        for (int i = 0; i < 16; ++i) if (!(i & 4)) x += a[i] * a[i | 4];
        x *= 2.f;
    }
}

// pubA: sender-side edge publish  (A-type, te{0,1,2,3,8,9,12}, <Z2>)
__device__ __forceinline__ float pubA(float chh, float shh,
                                      const float* cxv, const float* sxv,
                                      const float* teC, const float* teS) {
    float ic[4] = {chh, cxv[0], cxv[1], cxv[2]};
    float is[4] = {shh, sxv[0], sxv[1], sxv[2]};
    float thc[7] = {teC[0], teC[1], teC[2], teC[3], teC[8], teC[9], teC[12]};
    float ths[7] = {teS[0], teS[1], teS[2], teS[3], teS[8], teS[9], teS[12]};
    float z, x;
    sub16<false>(ic, is, thc, ths, z, x);
    return z;
}
// pubB: receiver-side edge publish (B-type, te{4,5,6,7,10,11,13}, <Z5>,<X5>)
__device__ __forceinline__ void pubB(float chh, float shh,
                                     const float* cxv, const float* sxv,
                                     const float* teC, const float* teS,
                                     float& z, float& x) {
    float ic[4] = {chh, cxv[0], cxv[1], cxv[2]};
    float is[4] = {shh, sxv[0], sxv[1], sxv[2]};
    float thc[7] = {teC[4], teC[5], teC[6], teC[7], teC[10], teC[11], teC[13]};
    float ths[7] = {teS[4], teS[5], teS[6], teS[7], teS[10], teS[11], teS[13]};
    sub16<true>(ic, is, thc, ths, z, x);
}
__device__ __forceinline__ void edge_pub(
        float chh, float shh, const float* cxv, const float* sxv,
        const float* teC, const float* teS,
        float& zA, float& zB, float& xB) {
    zA = pubA(chh, shh, cxv, sxv, teC, teS);
    pubB(chh, shh, cxv, sxv, teC, teS, zB, xB);
}

// node state update from gathered macc: zB9 from OLD h-trig; A1(mi), A2(mo);
// p9 -> new h; updates chh/shh in place. (verified r8/r9, absmax=0)
__device__ __forceinline__ float node_update(
        const float* M, float& chh, float& shh,
        const float* cxv, const float* sxv,
        const float* tnC, const float* tnS, float C20, float S20) {
    float zB9, dmy;
    {   // B (h,x: wires 8-11): tn{8,9,10,11,16,17,21}, <Z9>
        float ic[4] = {chh, cxv[0], cxv[1], cxv[2]};
        float is[4] = {shh, sxv[0], sxv[1], sxv[2]};
        float thc[7] = {tnC[8],tnC[9],tnC[10],tnC[11],tnC[16],tnC[17],tnC[21]};
        float ths[7] = {tnS[8],tnS[9],tnS[10],tnS[11],tnS[16],tnS[17],tnS[21]};
        sub16<true>(ic, is, thc, ths, zB9, dmy);
    }
    float mC[8], mS[8];
#pragma unroll
    for (int k = 0; k < 8; ++k) __sincosf(0.5f * M[k], &mS[k], &mC[k]);
    float zA1, zA2, xA2;
    {   // A1 (mi, wires 0-3): tn{0,1,2,3,12,13,18}, <Z2>
        float thc[7] = {tnC[0],tnC[1],tnC[2],tnC[3],tnC[12],tnC[13],tnC[18]};
        float ths[7] = {tnS[0],tnS[1],tnS[2],tnS[3],tnS[12],tnS[13],tnS[18]};
        sub16<false>(&mC[0], &mS[0], thc, ths, zA1, dmy);
    }
    {   // A2 (mo, wires 4-7): tn{4,5,6,7,14,15,19}, <Z5>,<X5>
        float thc[7] = {tnC[4],tnC[5],tnC[6],tnC[7],tnC[14],tnC[15],tnC[19]};
        float ths[7] = {tnS[4],tnS[5],tnS[6],tnS[7],tnS[14],tnS[15],tnS[19]};
        sub16<true>(&mC[4], &mS[4], thc, ths, zA2, xA2);
    }
    float p9 = (C20*zA1*zA2 - S20*xA2) * zB9;
    float h = PI_F * (1.f - p9);
    __sincosf(0.5f*h, &shh, &chh);
    return h;
}

// ---------------- setup: H0 + pub0 + indices + deg + theta trig ------------
// One float4-pair per thread (2M threads): HBM-bound scan of Ri/Ro (64 MB).
// Node-init work (tid<2048) hides under the scan. Zero region pre-memset.
// (verbatim from r4 = best measured config)
__global__ __launch_bounds__(256) void k_setup(
        const float* __restrict__ X, const float* __restrict__ Ri,
        const float* __restrict__ Ro, const float* __restrict__ W,
        const float* __restrict__ b, const float* __restrict__ te,
        const float* __restrict__ tn,
        int* __restrict__ send, int* __restrict__ recv, float* __restrict__ H,
        float* __restrict__ pub, float* __restrict__ trig,
        int* __restrict__ deg) {
    int tid = blockIdx.x * blockDim.x + threadIdx.x;
    if (tid < N_NODES) {
        float x0 = X[tid*3+0], x1 = X[tid*3+1], x2 = X[tid*3+2];
        float z = x0*W[0] + x1*W[1] + x2*W[2] + b[0];
        float sg = 1.0f / (1.0f + __expf(-z));
        float h = sg * TWO_PI_F;
        ((float4*)H)[tid] = make_float4(h, x0, x1, x2);
        float chh, shh, cxv[3], sxv[3];
        __sincosf(0.5f*h,  &shh, &chh);
        __sincosf(0.5f*x0, &sxv[0], &cxv[0]);
        __sincosf(0.5f*x1, &sxv[1], &cxv[1]);
        __sincosf(0.5f*x2, &sxv[2], &cxv[2]);
        float teC[14], teS[14];
#pragma unroll
        for (int k = 0; k < 14; ++k) __sincosf(0.5f*te[k], &teS[k], &teC[k]);
        float zA, zB, xB;
        edge_pub(chh, shh, cxv, sxv, teC, teS, zA, zB, xB);
        pub[tid*4+0] = zA; pub[tid*4+1] = zB; pub[tid*4+2] = xB;
    }
    if (tid >= 4096 && tid < 4096 + 15) {        // edge theta trig table
        int i = tid - 4096; float s, c;
        __sincosf(0.5f * te[i], &s, &c);
        trig[i] = c; trig[16 + i] = s;
    }
    if (tid >= 4224 && tid < 4224 + 23) {        // node theta trig table
        int i = tid - 4224; float s, c;
        __sincosf(0.5f * tn[i], &s, &c);
        trig[32 + i] = c; trig[56 + i] = s;
    }
    const float4 vi = ((const float4*)Ri)[tid];
    const float4 vo = ((const float4*)Ro)[tid];
    int base = tid * 4;
    int n = base >> 12;             // row (E = 4096)
    int e = base & (N_EDGES - 1);   // col
    int cnt = 0;
    if (vi.x != 0.f) { recv[e+0] = n; ++cnt; }
    if (vi.y != 0.f) { recv[e+1] = n; ++cnt; }
    if (vi.z != 0.f) { recv[e+2] = n; ++cnt; }
    if (vi.w != 0.f) { recv[e+3] = n; ++cnt; }
    if (vo.x != 0.f) { send[e+0] = n; ++cnt; }
    if (vo.y != 0.f) { send[e+1] = n; ++cnt; }
    if (vo.z != 0.f) { send[e+2] = n; ++cnt; }
    if (vo.w != 0.f) { send[e+3] = n; ++cnt; }
    if (cnt) atomicAdd(&deg[n], cnt);   // deg[n] = indeg + outdeg
}

// edge scatter: mi[ri] += ev*H[si], mo[si] += ev*H[ri]; then drain own vmem
// queue (atomics performed at coherence point) and tick both arrival counters.
__device__ __forceinline__ void scatter8(float ev, const float4& Hs, const float4& Hr,
                                         int si, int ri,
                                         float* __restrict__ macc, int* __restrict__ arr) {
    atomicAdd(&macc[ri*8+0], ev*Hs.x); atomicAdd(&macc[ri*8+1], ev*Hs.y);
    atomicAdd(&macc[ri*8+2], ev*Hs.z); atomicAdd(&macc[ri*8+3], ev*Hs.w);
    atomicAdd(&macc[si*8+4], ev*Hr.x); atomicAdd(&macc[si*8+5], ev*Hr.y);
    atomicAdd(&macc[si*8+6], ev*Hr.z); atomicAdd(&macc[si*8+7], ev*Hr.w);
    asm volatile("s_waitcnt vmcnt(0)" ::: "memory");
    atomicAdd(&arr[ri], 1); atomicAdd(&arr[si], 1);
}

// ---------------- persistent dataflow kernel (r4 geometry, minus the last
// node->edge exchange) -------------------------------------------------------
// 96 blocks x 64 thr: blocks 0..63 = edge lanes (4096 edges), 64..95 = node
// lanes (2048 nodes, ONE round only). Chain:
//   E: ev0, scatter0 ->arrA-> N: h1, pub1 ->epoch-> E: ev1, scatter1 ->arrB->
//   E: redundant h2(si), h2(ri) + pubs locally -> out.   (no epoch-2)
// h2 feeds only out[e] (per-edge private) -> no cross-replica constraint.
__global__ __launch_bounds__(64) void k_mega(
        float* __restrict__ H, float* __restrict__ pub,
        const int* __restrict__ send, const int* __restrict__ recv,
        const float* __restrict__ trig,
        float* __restrict__ maccA, float* __restrict__ maccB,
        int* __restrict__ arrA, int* __restrict__ arrB,
        int* __restrict__ epoch, const int* __restrict__ deg,
        float* __restrict__ out) {
    int lane = threadIdx.x;
    int blk  = blockIdx.x;
    const float* teC = trig;      const float* teS = trig + 16;
    const float* tnC = trig + 32; const float* tnS = trig + 56;

    if (blk < 64) {
        // ================= EDGE thread: e = blk*64 + lane =================
        int e = blk * 64 + lane;
        int si = send[e], ri = recv[e];
        int dgs = deg[si], dgr = deg[ri];      // plain (boundary-published)
        float4 Hs = ((const float4*)H)[si];    // (h0, x0,x1,x2)
        float4 Hr = ((const float4*)H)[ri];
        float c14 = trig[14], s14 = trig[30];
        float C14 = c14*c14 - s14*s14;         // cos(te14)
        float S14 = 2.f*c14*s14;               // sin(te14)
        float C20 = tnC[20]*tnC[20] - tnS[20]*tnS[20];
        float S20 = 2.f*tnC[20]*tnS[20];
        // endpoint static x-trig (for the final local node_update/pubs)
        float cxs[3], sxs[3], cxr[3], sxr[3];
        __sincosf(0.5f*Hs.y, &sxs[0], &cxs[0]);
        __sincosf(0.5f*Hs.z, &sxs[1], &cxs[1]);
        __sincosf(0.5f*Hs.w, &sxs[2], &cxs[2]);
        __sincosf(0.5f*Hr.y, &sxr[0], &cxr[0]);
        __sincosf(0.5f*Hr.z, &sxr[1], &cxr[1]);
        __sincosf(0.5f*Hr.w, &sxr[2], &cxr[2]);

        // it 0: pub from k_setup (kernel boundary -> plain loads fine)
        float zA = pub[si*4+0], zB = pub[ri*4+1], xB = pub[ri*4+2];
        float ev = 0.5f*(1.f - (C14*zA*zB - S14*xB));
        scatter8(ev, Hs, Hr, si, ri, maccA, arrA);

        // it 1: wait endpoint nodes, reload mutable scalars agent-scope
        spin_ge(epoch + si, 1); spin_ge(epoch + ri, 1);
        zA = agent_load(&pub[si*4+0]);
        zB = agent_load(&pub[ri*4+1]);
        xB = agent_load(&pub[ri*4+2]);
        float h1s = agent_load(&H[si*4]);
        float h1r = agent_load(&H[ri*4]);
        Hs.x = h1s; Hr.x = h1r;
        ev = 0.5f*(1.f - (C14*zA*zB - S14*xB));
        scatter8(ev, Hs, Hr, si, ri, maccB, arrB);

        // h1 trig for the final zB9 (depends on own previous h only)
        float ch1s, sh1s, ch1r, sh1r;
        __sincosf(0.5f*h1s, &sh1s, &ch1s);
        __sincosf(0.5f*h1r, &sh1r, &ch1r);

        // final: no epoch-2 -- poll arrB, gather maccB, recompute h2 locally
        while (agent_load_i(arrB + si) < dgs || agent_load_i(arrB + ri) < dgr)
            __builtin_amdgcn_s_sleep(1);
        asm volatile("" ::: "memory");
        float Ms[8], Mr[8];
#pragma unroll
        for (int k = 0; k < 8; ++k) Ms[k] = agent_load(maccB + si*8 + k);
#pragma unroll
        for (int k = 0; k < 8; ++k) Mr[k] = agent_load(maccB + ri*8 + k);
        node_update(Ms, ch1s, sh1s, cxs, sxs, tnC, tnS, C20, S20);  // -> h2(si) trig
        node_update(Mr, ch1r, sh1r, cxr, sxr, tnC, tnS, C20, S20);  // -> h2(ri) trig
        zA = pubA(ch1s, sh1s, cxs, sxs, teC, teS);
        pubB(ch1r, sh1r, cxr, sxr, teC, teS, zB, xB);
        out[e] = 0.5f*(1.f - (C14*zA*zB - S14*xB));
    } else {
        // ============ NODE thread: n = (blk-64)*64 + lane, ONE round ========
        int n = (blk - 64) * 64 + lane;
        float4 Hn = ((const float4*)H)[n];
        float chh, shh, cxv[3], sxv[3];
        __sincosf(0.5f*Hn.x, &shh, &chh);
        __sincosf(0.5f*Hn.y, &sxv[0], &cxv[0]);
        __sincosf(0.5f*Hn.z, &sxv[1], &cxv[1]);
        __sincosf(0.5f*Hn.w, &sxv[2], &cxv[2]);
        int dg = deg[n];
        float C20 = tnC[20]*tnC[20] - tnS[20]*tnS[20];
        float S20 = 2.f*tnC[20]*tnS[20];

        // wait shadow: zB9 depends only on own h0
        float zB9, dmy;
        {
            float ic[4] = {chh, cxv[0], cxv[1], cxv[2]};
            float is[4] = {shh, sxv[0], sxv[1], sxv[2]};
            float thc[7] = {tnC[8],tnC[9],tnC[10],tnC[11],tnC[16],tnC[17],tnC[21]};
            float ths[7] = {tnS[8],tnS[9],tnS[10],tnS[11],tnS[16],tnS[17],tnS[21]};
            sub16<true>(ic, is, thc, ths, zB9, dmy);
        }
        spin_ge(arrA + n, dg);               // all my edges scattered (it 0)
        float M[8], mC[8], mS[8];
#pragma unroll
        for (int k = 0; k < 8; ++k) M[k] = agent_load(maccA + n*8 + k);
#pragma unroll
        for (int k = 0; k < 8; ++k) __sincosf(0.5f*M[k], &mS[k], &mC[k]);
        float zA1, zA2, xA2;
        {   // A1 (mi, wires 0-3): tn{0,1,2,3,12,13,18}, <Z2>
            float thc[7] = {tnC[0],tnC[1],tnC[2],tnC[3],tnC[12],tnC[13],tnC[18]};
            float ths[7] = {tnS[0],tnS[1],tnS[2],tnS[3],tnS[12],tnS[13],tnS[18]};
            sub16<false>(&mC[0], &mS[0], thc, ths, zA1, dmy);
        }
        {   // A2 (mo, wires 4-7): tn{4,5,6,7,14,15,19}, <Z5>,<X5>
            float thc[7] = {tnC[4],tnC[5],tnC[6],tnC[7],tnC[14],tnC[15],tnC[19]};
            float ths[7] = {tnS[4],tnS[5],tnS[6],tnS[7],tnS[14],tnS[15],tnS[19]};
            sub16<true>(&mC[4], &mS[4], thc, ths, zA2, xA2);
        }
        float p9 = (C20*zA1*zA2 - S20*xA2) * zB9;
        float h = PI_F * (1.f - p9);
        __sincosf(0.5f*h, &shh, &chh);
        float zAe, zBe, xBe;
        edge_pub(chh, shh, cxv, sxv, teC, teS, zAe, zBe, xBe);
        agent_store(&pub[n*4+0], zAe);
        agent_store(&pub[n*4+1], zBe);
        agent_store(&pub[n*4+2], xBe);
        agent_store(&H[n*4], h);
        asm volatile("s_waitcnt vmcnt(0)" ::: "memory");   // visible...
        agent_store_i(epoch + n, 1);                       // ...before tick
    }
}

extern "C" void kernel_launch(void* const* d_in, const int* in_sizes, int n_in,
                              void* d_out, int out_size, void* d_ws, size_t ws_size,
                              hipStream_t stream) {
    const float* X  = (const float*)d_in[0];
    const float* Ri = (const float*)d_in[1];
    const float* Ro = (const float*)d_in[2];
    const float* W  = (const float*)d_in[3];
    const float* b  = (const float*)d_in[4];
    const float* te = (const float*)d_in[5];
    const float* tn = (const float*)d_in[6];
    float* out = (float*)d_out;

    int*   send  = (int*)d_ws;                      // [4096]
    int*   recv  = send + N_EDGES;                  // [4096]
    float* H     = (float*)(recv + N_EDGES);        // [8192]  (16B-aligned)
    float* pub   = H + N_NODES * 4;                 // [8192]  zA,zB,xB,- per node
    float* trig  = pub + N_NODES * 4;               // [128]
    // ---- zero region (one memset, stream-ordered before k_setup) ----
    float* maccA = trig + 128;                      // [16384]
    float* maccB = maccA + N_NODES * 8;             // [16384]
    int*   arrA  = (int*)(maccB + N_NODES * 8);     // [2048]
    int*   arrB  = arrA + N_NODES;                  // [2048]
    int*   epoch = arrB + N_NODES;                  // [2048]
    int*   deg   = epoch + N_NODES;                 // [2048]
    size_t zbytes = (size_t)(2 * N_NODES * 8 + 4 * N_NODES) * sizeof(float);

    hipMemsetAsync((void*)maccA, 0, zbytes, stream);
    int total4 = (N_NODES * N_EDGES) / 4;           // one float4-pair per thread
    k_setup<<<total4 / 256, 256, 0, stream>>>(X, Ri, Ro, W, b, te, tn,
                                              send, recv, H, pub, trig, deg);
    k_mega<<<96, 64, 0, stream>>>(H, pub, send, recv, trig,
                                  maccA, maccB, arrA, arrB, epoch, deg, out);
}